// Round 4
// baseline (501.213 us; speedup 1.0000x reference)
//
#include <hip/hip_runtime.h>

#define NN 100000
#define NE 1600000
#define NF 512
#define NH 128
#define NC 64
#define NPART 782            // ceil(NN/128): partition = dst>>7 (128 nodes each)
#define NBH 782              // hist blocks, 2048 edges each
#define NBP 392              // part blocks, 4096 edges each
#define CONVB 288            // weight-conversion blocks
#define SORTBUF 2816         // partition size ~2048 +- 45 (17 sigma margin)

typedef __attribute__((ext_vector_type(8))) short bf16x8;
typedef __attribute__((ext_vector_type(4))) float f32x4;

static __device__ __forceinline__ unsigned short f2bf(float f) {
  unsigned int u = __float_as_uint(f);
  u += 0x7fffu + ((u >> 16) & 1u);   // RNE
  return (unsigned short)(u >> 16);
}
static __device__ __forceinline__ float bf2f(unsigned short s) {
  return __uint_as_float(((unsigned int)s) << 16);
}

// ---------------- zero partition totals ----------------
__global__ void k_zero0(int* __restrict__ p) {
  int i = blockIdx.x * 256 + threadIdx.x;
  if (i < NPART + 1) p[i] = 0;
}

// ---------------- K1: partition histogram (blocks 0..781) + weight conv (782..1069) ----------------
__global__ __launch_bounds__(256) void k_hist_conv(const int* __restrict__ ei,
                                                   int* __restrict__ partTotals,
                                                   const float* __restrict__ W1,
                                                   const float* __restrict__ W2,
                                                   unsigned short* __restrict__ W1t,
                                                   unsigned short* __restrict__ W2t) {
  int t = threadIdx.x;
  if (blockIdx.x < NBH) {
    __shared__ int hist[NPART];
    for (int i = t; i < NPART; i += 256) hist[i] = 0;
    __syncthreads();
    int base = blockIdx.x * 2048;
#pragma unroll
    for (int j = 0; j < 8; ++j) {
      int e = base + j * 256 + t;
      if (e < NE) atomicAdd(&hist[ei[NE + e] >> 7], 1);
    }
    __syncthreads();
    for (int i = t; i < NPART; i += 256)
      if (hist[i]) atomicAdd(&partTotals[i], hist[i]);
  } else {
    int i = (blockIdx.x - NBH) * 256 + t;
    if (i < NF * NH) {
      int k = i / NH, n = i % NH;
      W1t[n * NF + k] = f2bf(W1[i]);
    }
    int j = i - NF * NH;
    if (j >= 0 && j < NH * NC) {
      int k = j / NC, n = j % NC;
      W2t[n * NH + k] = f2bf(W2[j]);
    }
  }
}

// ---------------- scan partition totals -> starts & cursors ----------------
__global__ __launch_bounds__(1024) void k_pscan(const int* __restrict__ partTotals,
                                                int* __restrict__ partStart,
                                                int* __restrict__ partCursor,
                                                int* __restrict__ rowptr) {
  __shared__ int sd[1024];
  int t = threadIdx.x;
  int v = (t < NPART) ? partTotals[t] : 0;
  sd[t] = v; __syncthreads();
  for (int o = 1; o < 1024; o <<= 1) {
    int y = (t >= o) ? sd[t - o] : 0;
    __syncthreads();
    sd[t] += y;
    __syncthreads();
  }
  int excl = sd[t] - v;
  if (t < NPART) { partStart[t] = excl; partCursor[t] = excl; }
  if (t == NPART - 1) partStart[NPART] = sd[t];  // == NE
  if (t == 0) rowptr[NN] = NE;
}

// ---------------- edge partition pass: run-coalesced writes into tmp ----------------
__global__ __launch_bounds__(256) void k_part(const int* __restrict__ ei,
                                              const float* __restrict__ ew,
                                              int* __restrict__ partCursor,
                                              int2* __restrict__ tmp) {
  __shared__ int hist[NPART];
  __shared__ int cur[NPART];
  int t = threadIdx.x;
  for (int i = t; i < NPART; i += 256) hist[i] = 0;
  __syncthreads();
  int base = blockIdx.x * 4096;
#pragma unroll
  for (int j = 0; j < 16; ++j) {
    int e = base + j * 256 + t;
    if (e < NE) atomicAdd(&hist[ei[NE + e] >> 7], 1);
  }
  __syncthreads();
  for (int i = t; i < NPART; i += 256) {
    int c = hist[i];
    cur[i] = c ? atomicAdd(&partCursor[i], c) : 0;
  }
  __syncthreads();
#pragma unroll
  for (int j = 0; j < 16; ++j) {
    int e = base + j * 256 + t;
    if (e < NE) {
      int d = ei[NE + e];
      int pos = atomicAdd(&cur[d >> 7], 1);
      // pack: src (bits 0..16) | dst_local (bits 20..26); w bits in .y
      tmp[pos] = make_int2(ei[e] | ((d & 127) << 20), __float_as_int(ew[e]));
    }
  }
}

// ---------------- K3: GEMM1 (blocks 0..781) + per-partition counting sort (782..1563) ----------------
// gemm1: h[NN][NH] bf16 = x[NN][NF] f32 @ W1 (128x128 tile, 16x16x32 MFMA), A reg-prefetched
// sortp blocks trail the grid and overlap with GEMM compute.
__global__ __launch_bounds__(256) void k_sortp_gemm1(const float* __restrict__ x,
                                                     const unsigned short* __restrict__ W1t,
                                                     unsigned short* __restrict__ h,
                                                     const int* __restrict__ partStart,
                                                     const int2* __restrict__ tmp,
                                                     int2* __restrict__ sedge,
                                                     int* __restrict__ rowptr) {
  __shared__ __align__(16) char smem[36864];
  int t = threadIdx.x;
  if (blockIdx.x < NPART) {
    // ---- GEMM1 tile ----
    typedef unsigned short row72[72];
    row72* As = (row72*)smem;                       // 128 x 72 shorts
    row72* Bs = (row72*)(smem + 128 * 72 * 2);      // 128 x 72 shorts
    int rowBase = blockIdx.x * 128;
    int wave = t >> 6, lane = t & 63;
    int wm = (wave & 1) * 64, wn = (wave >> 1) * 64;
    int lrow = lane & 15, quad = lane >> 4;
    int r0 = t >> 4, c4 = t & 15;     // staging coords: rows r0+i*16, col block c4

    f32x4 acc[4][4];
#pragma unroll
    for (int i = 0; i < 4; ++i)
#pragma unroll
      for (int j = 0; j < 4; ++j) acc[i][j] = (f32x4){0.f, 0.f, 0.f, 0.f};

    // prologue: prefetch A regs for k0 = 0
    float4 pa[8];
#pragma unroll
    for (int i = 0; i < 8; ++i) {
      int row = rowBase + r0 + i * 16; if (row >= NN) row = NN - 1;
      pa[i] = *(const float4*)(x + (size_t)row * NF + c4 * 4);
    }

    for (int k0 = 0; k0 < NF; k0 += 64) {
#pragma unroll
      for (int i = 0; i < 8; ++i) {           // stage A from prefetched regs (cvt to bf16)
        int r = r0 + i * 16;
        ushort4 sv;
        sv.x = f2bf(pa[i].x); sv.y = f2bf(pa[i].y); sv.z = f2bf(pa[i].z); sv.w = f2bf(pa[i].w);
        *(ushort4*)(&As[r][c4 * 4]) = sv;
      }
#pragma unroll
      for (int i = 0; i < 8; ++i) {           // stage B: 128x64 bf16 (L2-hot W1t)
        int n = r0 + i * 16;
        *(ushort4*)(&Bs[n][c4 * 4]) = *(const ushort4*)(W1t + n * NF + k0 + c4 * 4);
      }
      __syncthreads();
      if (k0 + 64 < NF) {                     // issue next-step A loads; latency hides under MFMA
#pragma unroll
        for (int i = 0; i < 8; ++i) {
          int row = rowBase + r0 + i * 16; if (row >= NN) row = NN - 1;
          pa[i] = *(const float4*)(x + (size_t)row * NF + (k0 + 64) + c4 * 4);
        }
      }
#pragma unroll
      for (int ks = 0; ks < 64; ks += 32) {
        bf16x8 a[4], b[4];
#pragma unroll
        for (int mt = 0; mt < 4; ++mt) a[mt] = *(const bf16x8*)(&As[wm + mt * 16 + lrow][ks + quad * 8]);
#pragma unroll
        for (int nt = 0; nt < 4; ++nt) b[nt] = *(const bf16x8*)(&Bs[wn + nt * 16 + lrow][ks + quad * 8]);
#pragma unroll
        for (int mt = 0; mt < 4; ++mt)
#pragma unroll
          for (int nt = 0; nt < 4; ++nt)
            acc[mt][nt] = __builtin_amdgcn_mfma_f32_16x16x32_bf16(a[mt], b[nt], acc[mt][nt], 0, 0, 0);
      }
      __syncthreads();
    }
#pragma unroll
    for (int mt = 0; mt < 4; ++mt)
#pragma unroll
      for (int nt = 0; nt < 4; ++nt)
#pragma unroll
        for (int r = 0; r < 4; ++r) {
          int row = rowBase + wm + mt * 16 + quad * 4 + r;
          if (row < NN) {
            int col = wn + nt * 16 + lrow;
            h[(size_t)row * NH + col] = f2bf(acc[mt][nt][r]);
          }
        }
  } else {
    // ---- per-partition counting sort by node (128 bins) ----
    int* cnt = (int*)smem;                 // 128
    int* sc = cnt + 128;                   // 128
    int* wcur = sc + 128;                  // 128
    int2* sorted = (int2*)(smem + 1536);   // SORTBUF x int2 (22528 B); total 24064 <= 36864
    int p = blockIdx.x - NPART;
    int r0 = partStart[p], r1 = partStart[p + 1];
    int n = r1 - r0;
    if (t < 128) cnt[t] = 0;
    __syncthreads();
    for (int i = t; i < n; i += 256) {
      int2 v = tmp[r0 + i];
      atomicAdd(&cnt[v.x >> 20], 1);
    }
    __syncthreads();
    if (t < 128) sc[t] = cnt[t];
    __syncthreads();
    for (int o = 1; o < 128; o <<= 1) {
      int y = (t >= o && t < 128) ? sc[t - o] : 0;
      __syncthreads();
      if (t < 128) sc[t] += y;
      __syncthreads();
    }
    if (t < 128) {
      int excl = sc[t] - cnt[t];
      int node = p * 128 + t;
      if (node < NN) rowptr[node] = r0 + excl;
      wcur[t] = excl;
    }
    __syncthreads();
    for (int i = t; i < n; i += 256) {
      int2 v = tmp[r0 + i];                       // L2-hot re-read
      int lpos = atomicAdd(&wcur[v.x >> 20], 1);
      sorted[lpos] = make_int2(v.x & 0xFFFFF, v.y);
    }
    __syncthreads();
    for (int i = t; i < n; i += 256) sedge[r0 + i] = sorted[i];
  }
}

// ---------------- GEMM2: h3[NN][NC] bf16 = h2[NN][NH] bf16 @ W2 ----------------
__global__ __launch_bounds__(256) void k_gemm2(const unsigned short* __restrict__ h2,
                                               const unsigned short* __restrict__ W2t,
                                               unsigned short* __restrict__ h3) {
  __shared__ __align__(16) unsigned short As[256][72];
  __shared__ __align__(16) unsigned short Bs[64][72];
  int t = threadIdx.x;
  int rowBase = blockIdx.x * 256;
  int wave = t >> 6, lane = t & 63;
  int wm = wave * 64;
  int lrow = lane & 15, quad = lane >> 4;

  f32x4 acc[4][4];
#pragma unroll
  for (int i = 0; i < 4; ++i)
#pragma unroll
    for (int j = 0; j < 4; ++j) acc[i][j] = (f32x4){0.f, 0.f, 0.f, 0.f};

  for (int k0 = 0; k0 < NH; k0 += 64) {
#pragma unroll
    for (int i = 0; i < 16; ++i) {          // stage A: 256x64 bf16
      int idx = t + i * 256;
      int r = idx >> 4, c4 = idx & 15;
      int row = rowBase + r; if (row >= NN) row = NN - 1;
      *(ushort4*)(&As[r][c4 * 4]) = *(const ushort4*)(h2 + (size_t)row * NH + k0 + c4 * 4);
    }
#pragma unroll
    for (int i = 0; i < 4; ++i) {           // stage B: 64x64 bf16
      int idx = t + i * 256;
      int n = idx >> 4, c4 = idx & 15;
      *(ushort4*)(&Bs[n][c4 * 4]) = *(const ushort4*)(W2t + n * NH + k0 + c4 * 4);
    }
    __syncthreads();
#pragma unroll
    for (int ks = 0; ks < 64; ks += 32) {
      bf16x8 a[4], b[4];
#pragma unroll
      for (int mt = 0; mt < 4; ++mt) a[mt] = *(const bf16x8*)(&As[wm + mt * 16 + lrow][ks + quad * 8]);
#pragma unroll
      for (int nt = 0; nt < 4; ++nt) b[nt] = *(const bf16x8*)(&Bs[nt * 16 + lrow][ks + quad * 8]);
#pragma unroll
      for (int mt = 0; mt < 4; ++mt)
#pragma unroll
        for (int nt = 0; nt < 4; ++nt)
          acc[mt][nt] = __builtin_amdgcn_mfma_f32_16x16x32_bf16(a[mt], b[nt], acc[mt][nt], 0, 0, 0);
    }
    __syncthreads();
  }
#pragma unroll
  for (int mt = 0; mt < 4; ++mt)
#pragma unroll
    for (int nt = 0; nt < 4; ++nt)
#pragma unroll
      for (int r = 0; r < 4; ++r) {
        int row = rowBase + wm + mt * 16 + quad * 4 + r;
        if (row < NN) {
          int col = nt * 16 + lrow;
          h3[(size_t)row * NC + col] = f2bf(acc[mt][nt][r]);
        }
      }
}

// ---------------- propagate 1: h2 = relu(seg_sum(w * h[src]) + b1), D=128 ----------------
// 16 lanes/edge x uint4(16B), 4 edge slots x 4-unroll = 16 gathers in flight per wave
__global__ __launch_bounds__(256) void k_prop1(const int* __restrict__ rowptr,
                                               const int2* __restrict__ sedge,
                                               const unsigned short* __restrict__ h,
                                               const float* __restrict__ b1,
                                               unsigned short* __restrict__ h2) {
  __shared__ int2 se[4][64];
  int w = threadIdx.x >> 6, lane = threadIdx.x & 63;
  int q = lane >> 4, l4 = lane & 15;
  int node = blockIdx.x * 4 + w;
  int e0 = rowptr[node], e1 = rowptr[node + 1];
  float a[8];
#pragma unroll
  for (int k = 0; k < 8; ++k) a[k] = 0.f;
  const int2 z = make_int2(0, 0);
  for (int e = e0; e < e1; e += 64) {
    int cnt = e1 - e; if (cnt > 64) cnt = 64;
    if (lane < cnt) se[w][lane] = sedge[e + lane];
    asm volatile("s_waitcnt lgkmcnt(0)" ::: "memory");
    for (int j = 0; j < cnt; j += 16) {
      int2 ed[4];
      uint4 v[4];
      float wt[4];
#pragma unroll
      for (int s = 0; s < 4; ++s) {
        int idx = j + s * 4 + q;                     // <= 63 always
        ed[s] = (idx < cnt) ? se[w][idx] : z;
      }
#pragma unroll
      for (int s = 0; s < 4; ++s) {
        wt[s] = __int_as_float(ed[s].y);
        v[s] = *(const uint4*)(h + (size_t)ed[s].x * NH + l4 * 8);
      }
#pragma unroll
      for (int s = 0; s < 4; ++s) {
        a[0] += wt[s] * bf2f((unsigned short)(v[s].x & 0xffffu));
        a[1] += wt[s] * bf2f((unsigned short)(v[s].x >> 16));
        a[2] += wt[s] * bf2f((unsigned short)(v[s].y & 0xffffu));
        a[3] += wt[s] * bf2f((unsigned short)(v[s].y >> 16));
        a[4] += wt[s] * bf2f((unsigned short)(v[s].z & 0xffffu));
        a[5] += wt[s] * bf2f((unsigned short)(v[s].z >> 16));
        a[6] += wt[s] * bf2f((unsigned short)(v[s].w & 0xffffu));
        a[7] += wt[s] * bf2f((unsigned short)(v[s].w >> 16));
      }
    }
  }
#pragma unroll
  for (int k = 0; k < 8; ++k) {
    a[k] += __shfl_xor(a[k], 16);
    a[k] += __shfl_xor(a[k], 32);
  }
  if (q == 0) {
    float4 ba = *(const float4*)(b1 + l4 * 8);
    float4 bb = *(const float4*)(b1 + l4 * 8 + 4);
    float o0 = fmaxf(a[0] + ba.x, 0.f), o1 = fmaxf(a[1] + ba.y, 0.f);
    float o2 = fmaxf(a[2] + ba.z, 0.f), o3 = fmaxf(a[3] + ba.w, 0.f);
    float o4 = fmaxf(a[4] + bb.x, 0.f), o5 = fmaxf(a[5] + bb.y, 0.f);
    float o6 = fmaxf(a[6] + bb.z, 0.f), o7 = fmaxf(a[7] + bb.w, 0.f);
    uint4 pk;
    pk.x = ((unsigned int)f2bf(o1) << 16) | (unsigned int)f2bf(o0);
    pk.y = ((unsigned int)f2bf(o3) << 16) | (unsigned int)f2bf(o2);
    pk.z = ((unsigned int)f2bf(o5) << 16) | (unsigned int)f2bf(o4);
    pk.w = ((unsigned int)f2bf(o7) << 16) | (unsigned int)f2bf(o6);
    *(uint4*)(h2 + (size_t)node * NH + l4 * 8) = pk;
  }
}

// ---------------- propagate 2: out = seg_sum(w * h3[src]) + b2, D=64 ----------------
// 8 lanes/edge x uint4(16B), 8 edge slots x 4-unroll = 16 gathers in flight per wave
__global__ __launch_bounds__(256) void k_prop2(const int* __restrict__ rowptr,
                                               const int2* __restrict__ sedge,
                                               const unsigned short* __restrict__ h3,
                                               const float* __restrict__ b2,
                                               float* __restrict__ out) {
  __shared__ int2 se[4][64];
  int w = threadIdx.x >> 6, lane = threadIdx.x & 63;
  int o = lane >> 3, l8 = lane & 7;
  int node = blockIdx.x * 4 + w;
  int e0 = rowptr[node], e1 = rowptr[node + 1];
  float a[8];
#pragma unroll
  for (int k = 0; k < 8; ++k) a[k] = 0.f;
  const int2 z = make_int2(0, 0);
  for (int e = e0; e < e1; e += 64) {
    int cnt = e1 - e; if (cnt > 64) cnt = 64;
    if (lane < cnt) se[w][lane] = sedge[e + lane];
    asm volatile("s_waitcnt lgkmcnt(0)" ::: "memory");
    for (int j = 0; j < cnt; j += 32) {
      int2 ed[4];
      uint4 v[4];
      float wt[4];
#pragma unroll
      for (int s = 0; s < 4; ++s) {
        int idx = j + s * 8 + o;                     // <= 63 always
        ed[s] = (idx < cnt) ? se[w][idx] : z;
      }
#pragma unroll
      for (int s = 0; s < 4; ++s) {
        wt[s] = __int_as_float(ed[s].y);
        v[s] = *(const uint4*)(h3 + (size_t)ed[s].x * NC + l8 * 8);
      }
#pragma unroll
      for (int s = 0; s < 4; ++s) {
        a[0] += wt[s] * bf2f((unsigned short)(v[s].x & 0xffffu));
        a[1] += wt[s] * bf2f((unsigned short)(v[s].x >> 16));
        a[2] += wt[s] * bf2f((unsigned short)(v[s].y & 0xffffu));
        a[3] += wt[s] * bf2f((unsigned short)(v[s].y >> 16));
        a[4] += wt[s] * bf2f((unsigned short)(v[s].z & 0xffffu));
        a[5] += wt[s] * bf2f((unsigned short)(v[s].z >> 16));
        a[6] += wt[s] * bf2f((unsigned short)(v[s].w & 0xffffu));
        a[7] += wt[s] * bf2f((unsigned short)(v[s].w >> 16));
      }
    }
  }
#pragma unroll
  for (int k = 0; k < 8; ++k) {
    a[k] += __shfl_xor(a[k], 8);
    a[k] += __shfl_xor(a[k], 16);
    a[k] += __shfl_xor(a[k], 32);
  }
  if (o == 0) {
    float4 c0 = *(const float4*)(b2 + l8 * 8);
    float4 c1 = *(const float4*)(b2 + l8 * 8 + 4);
    float4 r0 = make_float4(a[0] + c0.x, a[1] + c0.y, a[2] + c0.z, a[3] + c0.w);
    float4 r1 = make_float4(a[4] + c1.x, a[5] + c1.y, a[6] + c1.z, a[7] + c1.w);
    *(float4*)(out + (size_t)node * NC + l8 * 8) = r0;
    *(float4*)(out + (size_t)node * NC + l8 * 8 + 4) = r1;
  }
}

extern "C" void kernel_launch(void* const* d_in, const int* in_sizes, int n_in,
                              void* d_out, int out_size, void* d_ws, size_t ws_size,
                              hipStream_t stream) {
  const float* x = (const float*)d_in[0];
  const int* ei = (const int*)d_in[1];   // int32 on device (harness convention)
  const float* ew = (const float*)d_in[2];
  const float* W1 = (const float*)d_in[3];
  const float* b1 = (const float*)d_in[4];
  const float* W2 = (const float*)d_in[5];
  const float* b2 = (const float*)d_in[6];
  float* out = (float*)d_out;

  char* ws = (char*)d_ws;
  size_t off = 0;
  auto alloc = [&](size_t bytes) {
    char* p = ws + off;
    off = (off + bytes + 255) & ~(size_t)255;
    return p;
  };
  unsigned short* W1t = (unsigned short*)alloc((size_t)NF * NH * 2);
  unsigned short* W2t = (unsigned short*)alloc((size_t)NH * NC * 2);
  unsigned short* h   = (unsigned short*)alloc((size_t)NN * NH * 2);
  unsigned short* h2  = (unsigned short*)alloc((size_t)NN * NH * 2);
  unsigned short* h3  = h;  // h dead after prop1; alias to save ws
  int* rowptr     = (int*)alloc((size_t)(NN + 1) * 4);
  int* partTotals = (int*)alloc((NPART + 1) * 4);
  int* partStart  = (int*)alloc((NPART + 1) * 4);
  int* partCursor = (int*)alloc((NPART + 1) * 4);
  int2* sedge     = (int2*)alloc((size_t)NE * 8);
  int2* tmp       = (int2*)alloc((size_t)NE * 8);

  k_zero0<<<4, 256, 0, stream>>>(partTotals);
  k_hist_conv<<<NBH + CONVB, 256, 0, stream>>>(ei, partTotals, W1, W2, W1t, W2t);
  k_pscan<<<1, 1024, 0, stream>>>(partTotals, partStart, partCursor, rowptr);
  k_part<<<NBP, 256, 0, stream>>>(ei, ew, partCursor, tmp);
  k_sortp_gemm1<<<NPART + NPART, 256, 0, stream>>>(x, W1t, h, partStart, tmp, sedge, rowptr);
  k_prop1<<<NN / 4, 256, 0, stream>>>(rowptr, sedge, h, b1, h2);
  k_gemm2<<<(NN + 255) / 256, 256, 0, stream>>>(h2, W2t, h3);
  k_prop2<<<NN / 4, 256, 0, stream>>>(rowptr, sedge, h3, b2, out);
}

// Round 5
// 495.252 us; speedup vs baseline: 1.0120x; 1.0120x over previous
//
#include <hip/hip_runtime.h>

#define NN 100000
#define NE 1600000
#define NF 512
#define NH 128
#define NC 64
#define NPART 782            // ceil(NN/128): partition = dst>>7 (128 nodes each)
#define NBH 782              // hist blocks, 2048 edges each
#define NBP 196              // part blocks, 8192 edges each
#define CONVB 288            // weight-conversion blocks
#define SORTBUF 2816         // partition size ~2048 +- 45 (17 sigma margin)
#define GSPLIT 391           // gemm1 tiles in each of the two fused launches

typedef __attribute__((ext_vector_type(8))) short bf16x8;
typedef __attribute__((ext_vector_type(4))) float f32x4;

static __device__ __forceinline__ unsigned short f2bf(float f) {
  unsigned int u = __float_as_uint(f);
  u += 0x7fffu + ((u >> 16) & 1u);   // RNE
  return (unsigned short)(u >> 16);
}
static __device__ __forceinline__ float bf2f(unsigned short s) {
  return __uint_as_float(((unsigned int)s) << 16);
}

// ---------------- zero partition totals ----------------
__global__ void k_zero0(int* __restrict__ p) {
  int i = blockIdx.x * 256 + threadIdx.x;
  if (i < NPART + 1) p[i] = 0;
}

// ---------------- K1: partition histogram (blocks 0..781) + weight conv (782..1069) ----------------
__global__ __launch_bounds__(256) void k_hist_conv(const int* __restrict__ ei,
                                                   int* __restrict__ partTotals,
                                                   const float* __restrict__ W1,
                                                   const float* __restrict__ W2,
                                                   unsigned short* __restrict__ W1t,
                                                   unsigned short* __restrict__ W2t) {
  int t = threadIdx.x;
  if (blockIdx.x < NBH) {
    __shared__ int hist[NPART];
    for (int i = t; i < NPART; i += 256) hist[i] = 0;
    __syncthreads();
    int base = blockIdx.x * 2048;
#pragma unroll
    for (int j = 0; j < 8; ++j) {
      int e = base + j * 256 + t;
      if (e < NE) atomicAdd(&hist[ei[NE + e] >> 7], 1);
    }
    __syncthreads();
    for (int i = t; i < NPART; i += 256)
      if (hist[i]) atomicAdd(&partTotals[i], hist[i]);
  } else {
    int i = (blockIdx.x - NBH) * 256 + t;
    if (i < NF * NH) {
      int k = i / NH, n = i % NH;
      W1t[n * NF + k] = f2bf(W1[i]);
    }
    int j = i - NF * NH;
    if (j >= 0 && j < NH * NC) {
      int k = j / NC, n = j % NC;
      W2t[n * NH + k] = f2bf(W2[j]);
    }
  }
}

// ---------------- scan partition totals -> starts & cursors ----------------
__global__ __launch_bounds__(1024) void k_pscan(const int* __restrict__ partTotals,
                                                int* __restrict__ partStart,
                                                int* __restrict__ partCursor,
                                                int* __restrict__ rowptr) {
  __shared__ int sd[1024];
  int t = threadIdx.x;
  int v = (t < NPART) ? partTotals[t] : 0;
  sd[t] = v; __syncthreads();
  for (int o = 1; o < 1024; o <<= 1) {
    int y = (t >= o) ? sd[t - o] : 0;
    __syncthreads();
    sd[t] += y;
    __syncthreads();
  }
  int excl = sd[t] - v;
  if (t < NPART) { partStart[t] = excl; partCursor[t] = excl; }
  if (t == NPART - 1) partStart[NPART] = sd[t];  // == NE
  if (t == 0) rowptr[NN] = NE;
}

// ---------------- GEMM1 tile body (shared by both fused launches) ----------------
static __device__ __forceinline__ void gemm1_tile(char* smem, int tile, int t,
                                                  const float* __restrict__ x,
                                                  const unsigned short* __restrict__ W1t,
                                                  unsigned short* __restrict__ h) {
  typedef unsigned short row72[72];
  row72* As = (row72*)smem;                       // 128 x 72 shorts
  row72* Bs = (row72*)(smem + 128 * 72 * 2);      // 128 x 72 shorts
  int rowBase = tile * 128;
  int wave = t >> 6, lane = t & 63;
  int wm = (wave & 1) * 64, wn = (wave >> 1) * 64;
  int lrow = lane & 15, quad = lane >> 4;
  int r0 = t >> 4, c4 = t & 15;     // staging coords: rows r0+i*16, col block c4

  f32x4 acc[4][4];
#pragma unroll
  for (int i = 0; i < 4; ++i)
#pragma unroll
    for (int j = 0; j < 4; ++j) acc[i][j] = (f32x4){0.f, 0.f, 0.f, 0.f};

  // prologue: prefetch A regs for k0 = 0
  float4 pa[8];
#pragma unroll
  for (int i = 0; i < 8; ++i) {
    int row = rowBase + r0 + i * 16; if (row >= NN) row = NN - 1;
    pa[i] = *(const float4*)(x + (size_t)row * NF + c4 * 4);
  }

  for (int k0 = 0; k0 < NF; k0 += 64) {
#pragma unroll
    for (int i = 0; i < 8; ++i) {           // stage A from prefetched regs (cvt to bf16)
      int r = r0 + i * 16;
      ushort4 sv;
      sv.x = f2bf(pa[i].x); sv.y = f2bf(pa[i].y); sv.z = f2bf(pa[i].z); sv.w = f2bf(pa[i].w);
      *(ushort4*)(&As[r][c4 * 4]) = sv;
    }
#pragma unroll
    for (int i = 0; i < 8; ++i) {           // stage B: 128x64 bf16 (L2-hot W1t)
      int n = r0 + i * 16;
      *(ushort4*)(&Bs[n][c4 * 4]) = *(const ushort4*)(W1t + n * NF + k0 + c4 * 4);
    }
    __syncthreads();
    if (k0 + 64 < NF) {                     // issue next-step A loads; latency hides under MFMA
#pragma unroll
      for (int i = 0; i < 8; ++i) {
        int row = rowBase + r0 + i * 16; if (row >= NN) row = NN - 1;
        pa[i] = *(const float4*)(x + (size_t)row * NF + (k0 + 64) + c4 * 4);
      }
    }
#pragma unroll
    for (int ks = 0; ks < 64; ks += 32) {
      bf16x8 a[4], b[4];
#pragma unroll
      for (int mt = 0; mt < 4; ++mt) a[mt] = *(const bf16x8*)(&As[wm + mt * 16 + lrow][ks + quad * 8]);
#pragma unroll
      for (int nt = 0; nt < 4; ++nt) b[nt] = *(const bf16x8*)(&Bs[wn + nt * 16 + lrow][ks + quad * 8]);
#pragma unroll
      for (int mt = 0; mt < 4; ++mt)
#pragma unroll
        for (int nt = 0; nt < 4; ++nt)
          acc[mt][nt] = __builtin_amdgcn_mfma_f32_16x16x32_bf16(a[mt], b[nt], acc[mt][nt], 0, 0, 0);
    }
    __syncthreads();
  }
#pragma unroll
  for (int mt = 0; mt < 4; ++mt)
#pragma unroll
    for (int nt = 0; nt < 4; ++nt)
#pragma unroll
      for (int r = 0; r < 4; ++r) {
        int row = rowBase + wm + mt * 16 + quad * 4 + r;
        if (row < NN) {
          int col = wn + nt * 16 + lrow;
          h[(size_t)row * NH + col] = f2bf(acc[mt][nt][r]);
        }
      }
}

// ---------------- launch A: edge partition pass (blocks 0..195) + GEMM1 tiles 0..390 ----------------
__global__ __launch_bounds__(256) void k_part_gemm1a(const int* __restrict__ ei,
                                                     const float* __restrict__ ew,
                                                     int* __restrict__ partCursor,
                                                     int2* __restrict__ tmp,
                                                     const float* __restrict__ x,
                                                     const unsigned short* __restrict__ W1t,
                                                     unsigned short* __restrict__ h) {
  __shared__ __align__(16) char smem[36864];
  int t = threadIdx.x;
  if (blockIdx.x < NBP) {
    // ---- edge partitioning: 8192 edges, two global passes, run-coalesced writes ----
    int* hist = (int*)smem;           // NPART ints
    int* cur = hist + NPART;          // NPART ints
    for (int i = t; i < NPART; i += 256) hist[i] = 0;
    __syncthreads();
    int base = blockIdx.x * 8192;
#pragma unroll
    for (int j = 0; j < 32; ++j) {
      int e = base + j * 256 + t;
      if (e < NE) atomicAdd(&hist[ei[NE + e] >> 7], 1);
    }
    __syncthreads();
    for (int i = t; i < NPART; i += 256) {
      int c = hist[i];
      cur[i] = c ? atomicAdd(&partCursor[i], c) : 0;
    }
    __syncthreads();
#pragma unroll
    for (int j = 0; j < 32; ++j) {
      int e = base + j * 256 + t;
      if (e < NE) {
        int d = ei[NE + e];
        int pos = atomicAdd(&cur[d >> 7], 1);
        // pack: src (bits 0..16) | dst_local (bits 20..26); w bits in .y
        tmp[pos] = make_int2(ei[e] | ((d & 127) << 20), __float_as_int(ew[e]));
      }
    }
  } else {
    gemm1_tile(smem, blockIdx.x - NBP, t, x, W1t, h);
  }
}

// ---------------- launch B: GEMM1 tiles 391..781 (blocks 0..390) + per-partition sort (391..1172) ----------------
__global__ __launch_bounds__(256) void k_gemm1b_sortp(const float* __restrict__ x,
                                                      const unsigned short* __restrict__ W1t,
                                                      unsigned short* __restrict__ h,
                                                      const int* __restrict__ partStart,
                                                      const int2* __restrict__ tmp,
                                                      int2* __restrict__ sedge,
                                                      int* __restrict__ rowptr) {
  __shared__ __align__(16) char smem[36864];
  int t = threadIdx.x;
  if (blockIdx.x < GSPLIT) {
    gemm1_tile(smem, blockIdx.x + GSPLIT, t, x, W1t, h);
  } else {
    // ---- per-partition counting sort by node (128 bins) ----
    int* cnt = (int*)smem;                 // 128
    int* sc = cnt + 128;                   // 128
    int* wcur = sc + 128;                  // 128
    int2* sorted = (int2*)(smem + 1536);   // SORTBUF x int2 (22528 B); total 24064 <= 36864
    int p = blockIdx.x - GSPLIT;
    int r0 = partStart[p], r1 = partStart[p + 1];
    int n = r1 - r0;
    if (t < 128) cnt[t] = 0;
    __syncthreads();
    for (int i = t; i < n; i += 256) {
      int2 v = tmp[r0 + i];
      atomicAdd(&cnt[v.x >> 20], 1);
    }
    __syncthreads();
    if (t < 128) sc[t] = cnt[t];
    __syncthreads();
    for (int o = 1; o < 128; o <<= 1) {
      int y = (t >= o && t < 128) ? sc[t - o] : 0;
      __syncthreads();
      if (t < 128) sc[t] += y;
      __syncthreads();
    }
    if (t < 128) {
      int excl = sc[t] - cnt[t];
      int node = p * 128 + t;
      if (node < NN) rowptr[node] = r0 + excl;
      wcur[t] = excl;
    }
    __syncthreads();
    for (int i = t; i < n; i += 256) {
      int2 v = tmp[r0 + i];                       // L2-hot re-read
      int lpos = atomicAdd(&wcur[v.x >> 20], 1);
      sorted[lpos] = make_int2(v.x & 0xFFFFF, v.y);
    }
    __syncthreads();
    for (int i = t; i < n; i += 256) sedge[r0 + i] = sorted[i];
  }
}

// ---------------- GEMM2: h3[NN][NC] bf16 = h2[NN][NH] bf16 @ W2 ----------------
__global__ __launch_bounds__(256) void k_gemm2(const unsigned short* __restrict__ h2,
                                               const unsigned short* __restrict__ W2t,
                                               unsigned short* __restrict__ h3) {
  __shared__ __align__(16) unsigned short As[256][72];
  __shared__ __align__(16) unsigned short Bs[64][72];
  int t = threadIdx.x;
  int rowBase = blockIdx.x * 256;
  int wave = t >> 6, lane = t & 63;
  int wm = wave * 64;
  int lrow = lane & 15, quad = lane >> 4;

  f32x4 acc[4][4];
#pragma unroll
  for (int i = 0; i < 4; ++i)
#pragma unroll
    for (int j = 0; j < 4; ++j) acc[i][j] = (f32x4){0.f, 0.f, 0.f, 0.f};

  for (int k0 = 0; k0 < NH; k0 += 64) {
#pragma unroll
    for (int i = 0; i < 16; ++i) {          // stage A: 256x64 bf16
      int idx = t + i * 256;
      int r = idx >> 4, c4 = idx & 15;
      int row = rowBase + r; if (row >= NN) row = NN - 1;
      *(ushort4*)(&As[r][c4 * 4]) = *(const ushort4*)(h2 + (size_t)row * NH + k0 + c4 * 4);
    }
#pragma unroll
    for (int i = 0; i < 4; ++i) {           // stage B: 64x64 bf16
      int idx = t + i * 256;
      int n = idx >> 4, c4 = idx & 15;
      *(ushort4*)(&Bs[n][c4 * 4]) = *(const ushort4*)(W2t + n * NH + k0 + c4 * 4);
    }
    __syncthreads();
#pragma unroll
    for (int ks = 0; ks < 64; ks += 32) {
      bf16x8 a[4], b[4];
#pragma unroll
      for (int mt = 0; mt < 4; ++mt) a[mt] = *(const bf16x8*)(&As[wm + mt * 16 + lrow][ks + quad * 8]);
#pragma unroll
      for (int nt = 0; nt < 4; ++nt) b[nt] = *(const bf16x8*)(&Bs[nt * 16 + lrow][ks + quad * 8]);
#pragma unroll
      for (int mt = 0; mt < 4; ++mt)
#pragma unroll
        for (int nt = 0; nt < 4; ++nt)
          acc[mt][nt] = __builtin_amdgcn_mfma_f32_16x16x32_bf16(a[mt], b[nt], acc[mt][nt], 0, 0, 0);
    }
    __syncthreads();
  }
#pragma unroll
  for (int mt = 0; mt < 4; ++mt)
#pragma unroll
    for (int nt = 0; nt < 4; ++nt)
#pragma unroll
      for (int r = 0; r < 4; ++r) {
        int row = rowBase + wm + mt * 16 + quad * 4 + r;
        if (row < NN) {
          int col = nt * 16 + lrow;
          h3[(size_t)row * NC + col] = f2bf(acc[mt][nt][r]);
        }
      }
}

// ---------------- propagate 1: h2 = relu(seg_sum(w * h[src]) + b1), D=128 ----------------
// 16 lanes/edge x uint4(16B), 4 edge slots x 2-unroll = 8 gathers in flight per wave
__global__ __launch_bounds__(256) void k_prop1(const int* __restrict__ rowptr,
                                               const int2* __restrict__ sedge,
                                               const unsigned short* __restrict__ h,
                                               const float* __restrict__ b1,
                                               unsigned short* __restrict__ h2) {
  __shared__ int2 se[4][64];
  int w = threadIdx.x >> 6, lane = threadIdx.x & 63;
  int q = lane >> 4, l4 = lane & 15;
  int node = blockIdx.x * 4 + w;
  int e0 = rowptr[node], e1 = rowptr[node + 1];
  float a[8];
#pragma unroll
  for (int k = 0; k < 8; ++k) a[k] = 0.f;
  for (int e = e0; e < e1; e += 64) {
    int cnt = e1 - e; if (cnt > 64) cnt = 64;
    if (lane < cnt) se[w][lane] = sedge[e + lane];
    asm volatile("s_waitcnt lgkmcnt(0)" ::: "memory");
    for (int j = 0; j < cnt; j += 8) {
      int i0 = j + q, i1 = j + 4 + q;                 // both <= 63 always
      int2 ed0 = (i0 < cnt) ? se[w][i0] : make_int2(0, 0);
      int2 ed1 = (i1 < cnt) ? se[w][i1] : make_int2(0, 0);
      float w0 = __int_as_float(ed0.y), w1 = __int_as_float(ed1.y);
      uint4 v0 = *(const uint4*)(h + (size_t)ed0.x * NH + l4 * 8);
      uint4 v1 = *(const uint4*)(h + (size_t)ed1.x * NH + l4 * 8);
      a[0] += w0 * bf2f((unsigned short)(v0.x & 0xffffu));
      a[1] += w0 * bf2f((unsigned short)(v0.x >> 16));
      a[2] += w0 * bf2f((unsigned short)(v0.y & 0xffffu));
      a[3] += w0 * bf2f((unsigned short)(v0.y >> 16));
      a[4] += w0 * bf2f((unsigned short)(v0.z & 0xffffu));
      a[5] += w0 * bf2f((unsigned short)(v0.z >> 16));
      a[6] += w0 * bf2f((unsigned short)(v0.w & 0xffffu));
      a[7] += w0 * bf2f((unsigned short)(v0.w >> 16));
      a[0] += w1 * bf2f((unsigned short)(v1.x & 0xffffu));
      a[1] += w1 * bf2f((unsigned short)(v1.x >> 16));
      a[2] += w1 * bf2f((unsigned short)(v1.y & 0xffffu));
      a[3] += w1 * bf2f((unsigned short)(v1.y >> 16));
      a[4] += w1 * bf2f((unsigned short)(v1.z & 0xffffu));
      a[5] += w1 * bf2f((unsigned short)(v1.z >> 16));
      a[6] += w1 * bf2f((unsigned short)(v1.w & 0xffffu));
      a[7] += w1 * bf2f((unsigned short)(v1.w >> 16));
    }
  }
#pragma unroll
  for (int k = 0; k < 8; ++k) {
    a[k] += __shfl_xor(a[k], 16);
    a[k] += __shfl_xor(a[k], 32);
  }
  if (q == 0) {
    float4 ba = *(const float4*)(b1 + l4 * 8);
    float4 bb = *(const float4*)(b1 + l4 * 8 + 4);
    float o0 = fmaxf(a[0] + ba.x, 0.f), o1 = fmaxf(a[1] + ba.y, 0.f);
    float o2 = fmaxf(a[2] + ba.z, 0.f), o3 = fmaxf(a[3] + ba.w, 0.f);
    float o4 = fmaxf(a[4] + bb.x, 0.f), o5 = fmaxf(a[5] + bb.y, 0.f);
    float o6 = fmaxf(a[6] + bb.z, 0.f), o7 = fmaxf(a[7] + bb.w, 0.f);
    uint4 pk;
    pk.x = ((unsigned int)f2bf(o1) << 16) | (unsigned int)f2bf(o0);
    pk.y = ((unsigned int)f2bf(o3) << 16) | (unsigned int)f2bf(o2);
    pk.z = ((unsigned int)f2bf(o5) << 16) | (unsigned int)f2bf(o4);
    pk.w = ((unsigned int)f2bf(o7) << 16) | (unsigned int)f2bf(o6);
    *(uint4*)(h2 + (size_t)node * NH + l4 * 8) = pk;
  }
}

// ---------------- propagate 2: out = seg_sum(w * h3[src]) + b2, D=64 ----------------
// 8 lanes/edge x uint4(16B), 8 edge slots x 2-unroll = 16 gathers in flight per wave
__global__ __launch_bounds__(256) void k_prop2(const int* __restrict__ rowptr,
                                               const int2* __restrict__ sedge,
                                               const unsigned short* __restrict__ h3,
                                               const float* __restrict__ b2,
                                               float* __restrict__ out) {
  __shared__ int2 se[4][64];
  int w = threadIdx.x >> 6, lane = threadIdx.x & 63;
  int o = lane >> 3, l8 = lane & 7;
  int node = blockIdx.x * 4 + w;
  int e0 = rowptr[node], e1 = rowptr[node + 1];
  float a[8];
#pragma unroll
  for (int k = 0; k < 8; ++k) a[k] = 0.f;
  for (int e = e0; e < e1; e += 64) {
    int cnt = e1 - e; if (cnt > 64) cnt = 64;
    if (lane < cnt) se[w][lane] = sedge[e + lane];
    asm volatile("s_waitcnt lgkmcnt(0)" ::: "memory");
    for (int j = 0; j < cnt; j += 16) {
      int i0 = j + o, i1 = j + 8 + o;                 // both <= 63 always
      int2 ed0 = (i0 < cnt) ? se[w][i0] : make_int2(0, 0);
      int2 ed1 = (i1 < cnt) ? se[w][i1] : make_int2(0, 0);
      float w0 = __int_as_float(ed0.y), w1 = __int_as_float(ed1.y);
      uint4 v0 = *(const uint4*)(h3 + (size_t)ed0.x * NC + l8 * 8);
      uint4 v1 = *(const uint4*)(h3 + (size_t)ed1.x * NC + l8 * 8);
      a[0] += w0 * bf2f((unsigned short)(v0.x & 0xffffu));
      a[1] += w0 * bf2f((unsigned short)(v0.x >> 16));
      a[2] += w0 * bf2f((unsigned short)(v0.y & 0xffffu));
      a[3] += w0 * bf2f((unsigned short)(v0.y >> 16));
      a[4] += w0 * bf2f((unsigned short)(v0.z & 0xffffu));
      a[5] += w0 * bf2f((unsigned short)(v0.z >> 16));
      a[6] += w0 * bf2f((unsigned short)(v0.w & 0xffffu));
      a[7] += w0 * bf2f((unsigned short)(v0.w >> 16));
      a[0] += w1 * bf2f((unsigned short)(v1.x & 0xffffu));
      a[1] += w1 * bf2f((unsigned short)(v1.x >> 16));
      a[2] += w1 * bf2f((unsigned short)(v1.y & 0xffffu));
      a[3] += w1 * bf2f((unsigned short)(v1.y >> 16));
      a[4] += w1 * bf2f((unsigned short)(v1.z & 0xffffu));
      a[5] += w1 * bf2f((unsigned short)(v1.z >> 16));
      a[6] += w1 * bf2f((unsigned short)(v1.w & 0xffffu));
      a[7] += w1 * bf2f((unsigned short)(v1.w >> 16));
    }
  }
#pragma unroll
  for (int k = 0; k < 8; ++k) {
    a[k] += __shfl_xor(a[k], 8);
    a[k] += __shfl_xor(a[k], 16);
    a[k] += __shfl_xor(a[k], 32);
  }
  if (o == 0) {
    float4 c0 = *(const float4*)(b2 + l8 * 8);
    float4 c1 = *(const float4*)(b2 + l8 * 8 + 4);
    float4 r0 = make_float4(a[0] + c0.x, a[1] + c0.y, a[2] + c0.z, a[3] + c0.w);
    float4 r1 = make_float4(a[4] + c1.x, a[5] + c1.y, a[6] + c1.z, a[7] + c1.w);
    *(float4*)(out + (size_t)node * NC + l8 * 8) = r0;
    *(float4*)(out + (size_t)node * NC + l8 * 8 + 4) = r1;
  }
}

extern "C" void kernel_launch(void* const* d_in, const int* in_sizes, int n_in,
                              void* d_out, int out_size, void* d_ws, size_t ws_size,
                              hipStream_t stream) {
  const float* x = (const float*)d_in[0];
  const int* ei = (const int*)d_in[1];   // int32 on device (harness convention)
  const float* ew = (const float*)d_in[2];
  const float* W1 = (const float*)d_in[3];
  const float* b1 = (const float*)d_in[4];
  const float* W2 = (const float*)d_in[5];
  const float* b2 = (const float*)d_in[6];
  float* out = (float*)d_out;

  char* ws = (char*)d_ws;
  size_t off = 0;
  auto alloc = [&](size_t bytes) {
    char* p = ws + off;
    off = (off + bytes + 255) & ~(size_t)255;
    return p;
  };
  unsigned short* W1t = (unsigned short*)alloc((size_t)NF * NH * 2);
  unsigned short* W2t = (unsigned short*)alloc((size_t)NH * NC * 2);
  unsigned short* h   = (unsigned short*)alloc((size_t)NN * NH * 2);
  unsigned short* h2  = (unsigned short*)alloc((size_t)NN * NH * 2);
  unsigned short* h3  = h;  // h dead after prop1; alias to save ws
  int* rowptr     = (int*)alloc((size_t)(NN + 1) * 4);
  int* partTotals = (int*)alloc((NPART + 1) * 4);
  int* partStart  = (int*)alloc((NPART + 1) * 4);
  int* partCursor = (int*)alloc((NPART + 1) * 4);
  int2* sedge     = (int2*)alloc((size_t)NE * 8);
  int2* tmp       = (int2*)alloc((size_t)NE * 8);

  k_zero0<<<4, 256, 0, stream>>>(partTotals);
  k_hist_conv<<<NBH + CONVB, 256, 0, stream>>>(ei, partTotals, W1, W2, W1t, W2t);
  k_pscan<<<1, 1024, 0, stream>>>(partTotals, partStart, partCursor, rowptr);
  k_part_gemm1a<<<NBP + GSPLIT, 256, 0, stream>>>(ei, ew, partCursor, tmp, x, W1t, h);
  k_gemm1b_sortp<<<GSPLIT + NPART, 256, 0, stream>>>(x, W1t, h, partStart, tmp, sedge, rowptr);
  k_prop1<<<NN / 4, 256, 0, stream>>>(rowptr, sedge, h, b1, h2);
  k_gemm2<<<(NN + 255) / 256, 256, 0, stream>>>(h2, W2t, h3);
  k_prop2<<<NN / 4, 256, 0, stream>>>(rowptr, sedge, h3, b2, out);
}

// Round 6
// 485.651 us; speedup vs baseline: 1.0320x; 1.0198x over previous
//
#include <hip/hip_runtime.h>

#define NN 100000
#define NE 1600000
#define NF 512
#define NH 128
#define NC 64
#define NPART 782            // ceil(NN/128): partition = dst>>7 (128 nodes each)
#define NBH 782              // hist blocks, 2048 edges each
#define NBP 196              // part blocks, 8192 edges each
#define CONVB 288            // weight-conversion blocks
#define SORTBUF 2816         // partition size ~2048 +- 45 (17 sigma margin)

typedef __attribute__((ext_vector_type(8))) short bf16x8;
typedef __attribute__((ext_vector_type(4))) float f32x4;

static __device__ __forceinline__ unsigned short f2bf(float f) {
  unsigned int u = __float_as_uint(f);
  u += 0x7fffu + ((u >> 16) & 1u);   // RNE
  return (unsigned short)(u >> 16);
}
static __device__ __forceinline__ float bf2f(unsigned short s) {
  return __uint_as_float(((unsigned int)s) << 16);
}

// ---------------- zero partition totals ----------------
__global__ void k_zero0(int* __restrict__ p) {
  int i = blockIdx.x * 256 + threadIdx.x;
  if (i < NPART + 1) p[i] = 0;
}

// ---------------- K1: partition histogram (blocks 0..781) + weight conv (782..1069) ----------------
__global__ __launch_bounds__(256) void k_hist_conv(const int* __restrict__ ei,
                                                   int* __restrict__ partTotals,
                                                   const float* __restrict__ W1,
                                                   const float* __restrict__ W2,
                                                   unsigned short* __restrict__ W1t,
                                                   unsigned short* __restrict__ W2t) {
  int t = threadIdx.x;
  if (blockIdx.x < NBH) {
    __shared__ int hist[NPART];
    for (int i = t; i < NPART; i += 256) hist[i] = 0;
    __syncthreads();
    int base = blockIdx.x * 2048;
#pragma unroll
    for (int j = 0; j < 8; ++j) {
      int e = base + j * 256 + t;
      if (e < NE) atomicAdd(&hist[ei[NE + e] >> 7], 1);
    }
    __syncthreads();
    for (int i = t; i < NPART; i += 256)
      if (hist[i]) atomicAdd(&partTotals[i], hist[i]);
  } else {
    int i = (blockIdx.x - NBH) * 256 + t;
    if (i < NF * NH) {
      int k = i / NH, n = i % NH;
      W1t[n * NF + k] = f2bf(W1[i]);
    }
    int j = i - NF * NH;
    if (j >= 0 && j < NH * NC) {
      int k = j / NC, n = j % NC;
      W2t[n * NH + k] = f2bf(W2[j]);
    }
  }
}

// ---------------- scan partition totals -> starts & cursors ----------------
__global__ __launch_bounds__(1024) void k_pscan(const int* __restrict__ partTotals,
                                                int* __restrict__ partStart,
                                                int* __restrict__ partCursor,
                                                int* __restrict__ rowptr) {
  __shared__ int sd[1024];
  int t = threadIdx.x;
  int v = (t < NPART) ? partTotals[t] : 0;
  sd[t] = v; __syncthreads();
  for (int o = 1; o < 1024; o <<= 1) {
    int y = (t >= o) ? sd[t - o] : 0;
    __syncthreads();
    sd[t] += y;
    __syncthreads();
  }
  int excl = sd[t] - v;
  if (t < NPART) { partStart[t] = excl; partCursor[t] = excl; }
  if (t == NPART - 1) partStart[NPART] = sd[t];  // == NE
  if (t == 0) rowptr[NN] = NE;
}

// ---------------- K3: edge partition pass (blocks 0..195) + GEMM1 (blocks 196..977) ----------------
// gemm1: h[NN][NH] bf16 = x[NN][NF] f32 @ W1 (128x128 tile, 16x16x32 MFMA)
// A-tile is register-prefetched TWO K-steps ahead (paA/paB) so the ~900cy HBM latency
// is fully covered by one K-step (~1200+cy) of stage+MFMA+barrier work.
__global__ __launch_bounds__(256) void k_part_gemm1(const int* __restrict__ ei,
                                                    const float* __restrict__ ew,
                                                    int* __restrict__ partCursor,
                                                    int2* __restrict__ tmp,
                                                    const float* __restrict__ x,
                                                    const unsigned short* __restrict__ W1t,
                                                    unsigned short* __restrict__ h) {
  __shared__ __align__(16) char smem[36864];
  int t = threadIdx.x;
  if (blockIdx.x < NBP) {
    // ---- edge partitioning: 8192 edges, two global passes, run-coalesced writes ----
    int* hist = (int*)smem;           // NPART ints
    int* cur = hist + NPART;          // NPART ints
    for (int i = t; i < NPART; i += 256) hist[i] = 0;
    __syncthreads();
    int base = blockIdx.x * 8192;
#pragma unroll
    for (int j = 0; j < 32; ++j) {
      int e = base + j * 256 + t;
      if (e < NE) atomicAdd(&hist[ei[NE + e] >> 7], 1);
    }
    __syncthreads();
    for (int i = t; i < NPART; i += 256) {
      int c = hist[i];
      cur[i] = c ? atomicAdd(&partCursor[i], c) : 0;
    }
    __syncthreads();
#pragma unroll
    for (int j = 0; j < 32; ++j) {
      int e = base + j * 256 + t;
      if (e < NE) {
        int d = ei[NE + e];
        int pos = atomicAdd(&cur[d >> 7], 1);
        // pack: src (bits 0..16) | dst_local (bits 20..26); w bits in .y
        tmp[pos] = make_int2(ei[e] | ((d & 127) << 20), __float_as_int(ew[e]));
      }
    }
  } else {
    // ---- GEMM1 tile ----
    typedef unsigned short row72[72];
    row72* As = (row72*)smem;                       // 128 x 72 shorts
    row72* Bs = (row72*)(smem + 128 * 72 * 2);      // 128 x 72 shorts
    int rowBase = (blockIdx.x - NBP) * 128;
    int wave = t >> 6, lane = t & 63;
    int wm = (wave & 1) * 64, wn = (wave >> 1) * 64;
    int lrow = lane & 15, quad = lane >> 4;
    int r0 = t >> 4, c4 = t & 15;     // staging coords: rows r0+i*16, col block c4

    f32x4 acc[4][4];
#pragma unroll
    for (int i = 0; i < 4; ++i)
#pragma unroll
      for (int j = 0; j < 4; ++j) acc[i][j] = (f32x4){0.f, 0.f, 0.f, 0.f};

    auto loadA = [&](float4* pa, int kk) {
#pragma unroll
      for (int i = 0; i < 8; ++i) {
        int row = rowBase + r0 + i * 16; if (row >= NN) row = NN - 1;
        pa[i] = *(const float4*)(x + (size_t)row * NF + kk + c4 * 4);
      }
    };
    auto stage = [&](const float4* pa, int kk) {
#pragma unroll
      for (int i = 0; i < 8; ++i) {           // stage A from prefetched regs (cvt to bf16)
        int r = r0 + i * 16;
        ushort4 sv;
        sv.x = f2bf(pa[i].x); sv.y = f2bf(pa[i].y); sv.z = f2bf(pa[i].z); sv.w = f2bf(pa[i].w);
        *(ushort4*)(&As[r][c4 * 4]) = sv;
      }
#pragma unroll
      for (int i = 0; i < 8; ++i) {           // stage B: 128x64 bf16 (L2-hot W1t)
        int n = r0 + i * 16;
        *(ushort4*)(&Bs[n][c4 * 4]) = *(const ushort4*)(W1t + n * NF + kk + c4 * 4);
      }
    };
    auto mfma_step = [&]() {
#pragma unroll
      for (int ks = 0; ks < 64; ks += 32) {
        bf16x8 a[4], b[4];
#pragma unroll
        for (int mt = 0; mt < 4; ++mt) a[mt] = *(const bf16x8*)(&As[wm + mt * 16 + lrow][ks + quad * 8]);
#pragma unroll
        for (int nt = 0; nt < 4; ++nt) b[nt] = *(const bf16x8*)(&Bs[wn + nt * 16 + lrow][ks + quad * 8]);
#pragma unroll
        for (int mt = 0; mt < 4; ++mt)
#pragma unroll
          for (int nt = 0; nt < 4; ++nt)
            acc[mt][nt] = __builtin_amdgcn_mfma_f32_16x16x32_bf16(a[mt], b[nt], acc[mt][nt], 0, 0, 0);
      }
    };

    // prologue: prefetch slices 0 and 64 (2-deep)
    float4 paA[8], paB[8];
    loadA(paA, 0);
    loadA(paB, 64);

    for (int k0 = 0; k0 < NF; k0 += 128) {
      // half 1: consume paA (slice k0); refill paA for slice k0+128
      stage(paA, k0);
      __syncthreads();
      if (k0 + 128 < NF) loadA(paA, k0 + 128);
      mfma_step();
      __syncthreads();
      // half 2: consume paB (slice k0+64); refill paB for slice k0+192
      stage(paB, k0 + 64);
      __syncthreads();
      if (k0 + 192 < NF) loadA(paB, k0 + 192);
      mfma_step();
      __syncthreads();
    }
#pragma unroll
    for (int mt = 0; mt < 4; ++mt)
#pragma unroll
      for (int nt = 0; nt < 4; ++nt)
#pragma unroll
        for (int r = 0; r < 4; ++r) {
          int row = rowBase + wm + mt * 16 + quad * 4 + r;
          if (row < NN) {
            int col = wn + nt * 16 + lrow;
            h[(size_t)row * NH + col] = f2bf(acc[mt][nt][r]);
          }
        }
  }
}

// ---------------- pass B: per-partition counting sort by node (128 bins) ----------------
__global__ __launch_bounds__(256) void k_sortp(const int* __restrict__ partStart,
                                               const int2* __restrict__ tmp,
                                               int2* __restrict__ sedge,
                                               int* __restrict__ rowptr) {
  __shared__ int cnt[128];
  __shared__ int sc[128];
  __shared__ int wcur[128];
  __shared__ int2 sorted[SORTBUF];
  int p = blockIdx.x, t = threadIdx.x;
  int r0 = partStart[p], r1 = partStart[p + 1];
  int n = r1 - r0;
  if (t < 128) cnt[t] = 0;
  __syncthreads();
  for (int i = t; i < n; i += 256) {
    int2 v = tmp[r0 + i];
    atomicAdd(&cnt[v.x >> 20], 1);
  }
  __syncthreads();
  if (t < 128) sc[t] = cnt[t];
  __syncthreads();
  for (int o = 1; o < 128; o <<= 1) {
    int y = (t >= o && t < 128) ? sc[t - o] : 0;
    __syncthreads();
    if (t < 128) sc[t] += y;
    __syncthreads();
  }
  if (t < 128) {
    int excl = sc[t] - cnt[t];
    int node = p * 128 + t;
    if (node < NN) rowptr[node] = r0 + excl;
    wcur[t] = excl;
  }
  __syncthreads();
  for (int i = t; i < n; i += 256) {
    int2 v = tmp[r0 + i];                       // L2-hot re-read
    int lpos = atomicAdd(&wcur[v.x >> 20], 1);
    sorted[lpos] = make_int2(v.x & 0xFFFFF, v.y);
  }
  __syncthreads();
  for (int i = t; i < n; i += 256) sedge[r0 + i] = sorted[i];
}

// ---------------- GEMM2: h3[NN][NC] bf16 = h2[NN][NH] bf16 @ W2 ----------------
__global__ __launch_bounds__(256) void k_gemm2(const unsigned short* __restrict__ h2,
                                               const unsigned short* __restrict__ W2t,
                                               unsigned short* __restrict__ h3) {
  __shared__ __align__(16) unsigned short As[256][72];
  __shared__ __align__(16) unsigned short Bs[64][72];
  int t = threadIdx.x;
  int rowBase = blockIdx.x * 256;
  int wave = t >> 6, lane = t & 63;
  int wm = wave * 64;
  int lrow = lane & 15, quad = lane >> 4;

  f32x4 acc[4][4];
#pragma unroll
  for (int i = 0; i < 4; ++i)
#pragma unroll
    for (int j = 0; j < 4; ++j) acc[i][j] = (f32x4){0.f, 0.f, 0.f, 0.f};

  for (int k0 = 0; k0 < NH; k0 += 64) {
#pragma unroll
    for (int i = 0; i < 16; ++i) {          // stage A: 256x64 bf16
      int idx = t + i * 256;
      int r = idx >> 4, c4 = idx & 15;
      int row = rowBase + r; if (row >= NN) row = NN - 1;
      *(ushort4*)(&As[r][c4 * 4]) = *(const ushort4*)(h2 + (size_t)row * NH + k0 + c4 * 4);
    }
#pragma unroll
    for (int i = 0; i < 4; ++i) {           // stage B: 64x64 bf16
      int idx = t + i * 256;
      int n = idx >> 4, c4 = idx & 15;
      *(ushort4*)(&Bs[n][c4 * 4]) = *(const ushort4*)(W2t + n * NH + k0 + c4 * 4);
    }
    __syncthreads();
#pragma unroll
    for (int ks = 0; ks < 64; ks += 32) {
      bf16x8 a[4], b[4];
#pragma unroll
      for (int mt = 0; mt < 4; ++mt) a[mt] = *(const bf16x8*)(&As[wm + mt * 16 + lrow][ks + quad * 8]);
#pragma unroll
      for (int nt = 0; nt < 4; ++nt) b[nt] = *(const bf16x8*)(&Bs[nt * 16 + lrow][ks + quad * 8]);
#pragma unroll
      for (int mt = 0; mt < 4; ++mt)
#pragma unroll
        for (int nt = 0; nt < 4; ++nt)
          acc[mt][nt] = __builtin_amdgcn_mfma_f32_16x16x32_bf16(a[mt], b[nt], acc[mt][nt], 0, 0, 0);
    }
    __syncthreads();
  }
#pragma unroll
  for (int mt = 0; mt < 4; ++mt)
#pragma unroll
    for (int nt = 0; nt < 4; ++nt)
#pragma unroll
      for (int r = 0; r < 4; ++r) {
        int row = rowBase + wm + mt * 16 + quad * 4 + r;
        if (row < NN) {
          int col = nt * 16 + lrow;
          h3[(size_t)row * NC + col] = f2bf(acc[mt][nt][r]);
        }
      }
}

// ---------------- propagate 1: h2 = relu(seg_sum(w * h[src]) + b1), D=128 ----------------
// 16 lanes/edge x uint4(16B), 2-deep = 8 gathers in flight per wave
__global__ __launch_bounds__(256) void k_prop1(const int* __restrict__ rowptr,
                                               const int2* __restrict__ sedge,
                                               const unsigned short* __restrict__ h,
                                               const float* __restrict__ b1,
                                               unsigned short* __restrict__ h2) {
  __shared__ int2 se[4][64];
  int w = threadIdx.x >> 6, lane = threadIdx.x & 63;
  int q = lane >> 4, l4 = lane & 15;
  int node = blockIdx.x * 4 + w;
  int e0 = rowptr[node], e1 = rowptr[node + 1];
  float a[8];
#pragma unroll
  for (int k = 0; k < 8; ++k) a[k] = 0.f;
  for (int e = e0; e < e1; e += 64) {
    int cnt = e1 - e; if (cnt > 64) cnt = 64;
    if (lane < cnt) se[w][lane] = sedge[e + lane];
    asm volatile("s_waitcnt lgkmcnt(0)" ::: "memory");
    for (int j = 0; j < cnt; j += 8) {
      int i0 = j + q, i1 = j + 4 + q;                 // both <= 63 always
      int2 ed0 = (i0 < cnt) ? se[w][i0] : make_int2(0, 0);
      int2 ed1 = (i1 < cnt) ? se[w][i1] : make_int2(0, 0);
      float w0 = __int_as_float(ed0.y), w1 = __int_as_float(ed1.y);
      uint4 v0 = *(const uint4*)(h + (size_t)ed0.x * NH + l4 * 8);
      uint4 v1 = *(const uint4*)(h + (size_t)ed1.x * NH + l4 * 8);
      a[0] += w0 * bf2f((unsigned short)(v0.x & 0xffffu));
      a[1] += w0 * bf2f((unsigned short)(v0.x >> 16));
      a[2] += w0 * bf2f((unsigned short)(v0.y & 0xffffu));
      a[3] += w0 * bf2f((unsigned short)(v0.y >> 16));
      a[4] += w0 * bf2f((unsigned short)(v0.z & 0xffffu));
      a[5] += w0 * bf2f((unsigned short)(v0.z >> 16));
      a[6] += w0 * bf2f((unsigned short)(v0.w & 0xffffu));
      a[7] += w0 * bf2f((unsigned short)(v0.w >> 16));
      a[0] += w1 * bf2f((unsigned short)(v1.x & 0xffffu));
      a[1] += w1 * bf2f((unsigned short)(v1.x >> 16));
      a[2] += w1 * bf2f((unsigned short)(v1.y & 0xffffu));
      a[3] += w1 * bf2f((unsigned short)(v1.y >> 16));
      a[4] += w1 * bf2f((unsigned short)(v1.z & 0xffffu));
      a[5] += w1 * bf2f((unsigned short)(v1.z >> 16));
      a[6] += w1 * bf2f((unsigned short)(v1.w & 0xffffu));
      a[7] += w1 * bf2f((unsigned short)(v1.w >> 16));
    }
  }
#pragma unroll
  for (int k = 0; k < 8; ++k) {
    a[k] += __shfl_xor(a[k], 16);
    a[k] += __shfl_xor(a[k], 32);
  }
  if (q == 0) {
    float4 ba = *(const float4*)(b1 + l4 * 8);
    float4 bb = *(const float4*)(b1 + l4 * 8 + 4);
    float o0 = fmaxf(a[0] + ba.x, 0.f), o1 = fmaxf(a[1] + ba.y, 0.f);
    float o2 = fmaxf(a[2] + ba.z, 0.f), o3 = fmaxf(a[3] + ba.w, 0.f);
    float o4 = fmaxf(a[4] + bb.x, 0.f), o5 = fmaxf(a[5] + bb.y, 0.f);
    float o6 = fmaxf(a[6] + bb.z, 0.f), o7 = fmaxf(a[7] + bb.w, 0.f);
    uint4 pk;
    pk.x = ((unsigned int)f2bf(o1) << 16) | (unsigned int)f2bf(o0);
    pk.y = ((unsigned int)f2bf(o3) << 16) | (unsigned int)f2bf(o2);
    pk.z = ((unsigned int)f2bf(o5) << 16) | (unsigned int)f2bf(o4);
    pk.w = ((unsigned int)f2bf(o7) << 16) | (unsigned int)f2bf(o6);
    *(uint4*)(h2 + (size_t)node * NH + l4 * 8) = pk;
  }
}

// ---------------- propagate 2: out = seg_sum(w * h3[src]) + b2, D=64 ----------------
// 8 lanes/edge x uint4(16B), 2-deep = 16 gathers in flight per wave
__global__ __launch_bounds__(256) void k_prop2(const int* __restrict__ rowptr,
                                               const int2* __restrict__ sedge,
                                               const unsigned short* __restrict__ h3,
                                               const float* __restrict__ b2,
                                               float* __restrict__ out) {
  __shared__ int2 se[4][64];
  int w = threadIdx.x >> 6, lane = threadIdx.x & 63;
  int o = lane >> 3, l8 = lane & 7;
  int node = blockIdx.x * 4 + w;
  int e0 = rowptr[node], e1 = rowptr[node + 1];
  float a[8];
#pragma unroll
  for (int k = 0; k < 8; ++k) a[k] = 0.f;
  for (int e = e0; e < e1; e += 64) {
    int cnt = e1 - e; if (cnt > 64) cnt = 64;
    if (lane < cnt) se[w][lane] = sedge[e + lane];
    asm volatile("s_waitcnt lgkmcnt(0)" ::: "memory");
    for (int j = 0; j < cnt; j += 16) {
      int i0 = j + o, i1 = j + 8 + o;                 // both <= 63 always
      int2 ed0 = (i0 < cnt) ? se[w][i0] : make_int2(0, 0);
      int2 ed1 = (i1 < cnt) ? se[w][i1] : make_int2(0, 0);
      float w0 = __int_as_float(ed0.y), w1 = __int_as_float(ed1.y);
      uint4 v0 = *(const uint4*)(h3 + (size_t)ed0.x * NC + l8 * 8);
      uint4 v1 = *(const uint4*)(h3 + (size_t)ed1.x * NC + l8 * 8);
      a[0] += w0 * bf2f((unsigned short)(v0.x & 0xffffu));
      a[1] += w0 * bf2f((unsigned short)(v0.x >> 16));
      a[2] += w0 * bf2f((unsigned short)(v0.y & 0xffffu));
      a[3] += w0 * bf2f((unsigned short)(v0.y >> 16));
      a[4] += w0 * bf2f((unsigned short)(v0.z & 0xffffu));
      a[5] += w0 * bf2f((unsigned short)(v0.z >> 16));
      a[6] += w0 * bf2f((unsigned short)(v0.w & 0xffffu));
      a[7] += w0 * bf2f((unsigned short)(v0.w >> 16));
      a[0] += w1 * bf2f((unsigned short)(v1.x & 0xffffu));
      a[1] += w1 * bf2f((unsigned short)(v1.x >> 16));
      a[2] += w1 * bf2f((unsigned short)(v1.y & 0xffffu));
      a[3] += w1 * bf2f((unsigned short)(v1.y >> 16));
      a[4] += w1 * bf2f((unsigned short)(v1.z & 0xffffu));
      a[5] += w1 * bf2f((unsigned short)(v1.z >> 16));
      a[6] += w1 * bf2f((unsigned short)(v1.w & 0xffffu));
      a[7] += w1 * bf2f((unsigned short)(v1.w >> 16));
    }
  }
#pragma unroll
  for (int k = 0; k < 8; ++k) {
    a[k] += __shfl_xor(a[k], 8);
    a[k] += __shfl_xor(a[k], 16);
    a[k] += __shfl_xor(a[k], 32);
  }
  if (o == 0) {
    float4 c0 = *(const float4*)(b2 + l8 * 8);
    float4 c1 = *(const float4*)(b2 + l8 * 8 + 4);
    float4 r0 = make_float4(a[0] + c0.x, a[1] + c0.y, a[2] + c0.z, a[3] + c0.w);
    float4 r1 = make_float4(a[4] + c1.x, a[5] + c1.y, a[6] + c1.z, a[7] + c1.w);
    *(float4*)(out + (size_t)node * NC + l8 * 8) = r0;
    *(float4*)(out + (size_t)node * NC + l8 * 8 + 4) = r1;
  }
}

extern "C" void kernel_launch(void* const* d_in, const int* in_sizes, int n_in,
                              void* d_out, int out_size, void* d_ws, size_t ws_size,
                              hipStream_t stream) {
  const float* x = (const float*)d_in[0];
  const int* ei = (const int*)d_in[1];   // int32 on device (harness convention)
  const float* ew = (const float*)d_in[2];
  const float* W1 = (const float*)d_in[3];
  const float* b1 = (const float*)d_in[4];
  const float* W2 = (const float*)d_in[5];
  const float* b2 = (const float*)d_in[6];
  float* out = (float*)d_out;

  char* ws = (char*)d_ws;
  size_t off = 0;
  auto alloc = [&](size_t bytes) {
    char* p = ws + off;
    off = (off + bytes + 255) & ~(size_t)255;
    return p;
  };
  unsigned short* W1t = (unsigned short*)alloc((size_t)NF * NH * 2);
  unsigned short* W2t = (unsigned short*)alloc((size_t)NH * NC * 2);
  unsigned short* h   = (unsigned short*)alloc((size_t)NN * NH * 2);
  unsigned short* h2  = (unsigned short*)alloc((size_t)NN * NH * 2);
  unsigned short* h3  = h;  // h dead after prop1; alias to save ws
  int* rowptr     = (int*)alloc((size_t)(NN + 1) * 4);
  int* partTotals = (int*)alloc((NPART + 1) * 4);
  int* partStart  = (int*)alloc((NPART + 1) * 4);
  int* partCursor = (int*)alloc((NPART + 1) * 4);
  int2* sedge     = (int2*)alloc((size_t)NE * 8);
  int2* tmp       = (int2*)alloc((size_t)NE * 8);

  k_zero0<<<4, 256, 0, stream>>>(partTotals);
  k_hist_conv<<<NBH + CONVB, 256, 0, stream>>>(ei, partTotals, W1, W2, W1t, W2t);
  k_pscan<<<1, 1024, 0, stream>>>(partTotals, partStart, partCursor, rowptr);
  k_part_gemm1<<<NBP + 782, 256, 0, stream>>>(ei, ew, partCursor, tmp, x, W1t, h);
  k_sortp<<<NPART, 256, 0, stream>>>(partStart, tmp, sedge, rowptr);
  k_prop1<<<NN / 4, 256, 0, stream>>>(rowptr, sedge, h, b1, h2);
  k_gemm2<<<(NN + 255) / 256, 256, 0, stream>>>(h2, W2t, h3);
  k_prop2<<<NN / 4, 256, 0, stream>>>(rowptr, sedge, h3, b2, out);
}